// Round 1
// baseline (198.960 us; speedup 1.0000x reference)
//
#include <hip/hip_runtime.h>
#include <math.h>

#define S 76
#define A 3
#define CH 85            // 5 + 80
#define NCLS 80
#define MAXGT 150
#define CELLS_PER_BATCH (S * S * A)   // 17328
#define BLK 256

__device__ __forceinline__ float frcp(float x) { return __builtin_amdgcn_rcpf(x); }
__device__ __forceinline__ float sigmoidf_(float x) { return frcp(1.f + __expf(-x)); }
// bce_with_logits(x, y) = max(x,0) - x*y + log1p(exp(-|x|))
__device__ __forceinline__ float bcef(float x, float y) {
    return fmaxf(x, 0.f) - x * y + __logf(1.f + __expf(-fabsf(x)));
}

// Stage 1: one thread per anchor-cell; per-block partial sums -> d_ws.
__global__ __launch_bounds__(BLK) void yolo_loss_kernel(
    const float* __restrict__ conv, const float* __restrict__ label,
    const float* __restrict__ bboxes, float* __restrict__ part)
{
    const int b = blockIdx.y;
    int t = blockIdx.x * BLK + threadIdx.x;
    const bool valid = (t < CELLS_PER_BATCH);
    if (t >= CELLS_PER_BATCH) t = CELLS_PER_BATCH - 1;   // clamp: keep loads uniform-path

    const int i   = t / (S * A);           // row (grid y)
    const int rem = t - i * (S * A);
    const int j   = rem / A;               // col (grid x)
    const int a   = rem - j * A;           // anchor

    const size_t cell = (size_t)b * CELLS_PER_BATCH + (size_t)t;
    const float* cv = conv  + cell * CH;
    const float* lb = label + cell * CH;

    const float dx = cv[0], dy = cv[1], dw = cv[2], dh = cv[3], rc = cv[4];
    const float lx = lb[0], ly = lb[1], lw = lb[2], lh = lb[3], resp = lb[4];

    const float aw = (a == 0) ? 12.f : ((a == 1) ? 19.f : 40.f);
    const float ah = (a == 0) ? 16.f : ((a == 1) ? 36.f : 28.f);

    // decode
    const float px = (sigmoidf_(dx) * 1.2f - 0.1f + (float)j) * 8.f;
    const float py = (sigmoidf_(dy) * 1.2f - 0.1f + (float)i) * 8.f;
    const float pw = __expf(dw) * aw;
    const float ph = __expf(dh) * ah;
    const float pconf = sigmoidf_(rc);

    // ---- GIoU(pred, label) ----
    const float px1 = px - pw * 0.5f, py1 = py - ph * 0.5f;
    const float px2 = px + pw * 0.5f, py2 = py + ph * 0.5f;
    const float lx1 = lx - lw * 0.5f, ly1 = ly - lh * 0.5f;
    const float lx2 = lx + lw * 0.5f, ly2 = ly + lh * 0.5f;
    const float areap = pw * ph, areal = lw * lh;
    const float iw = fmaxf(fminf(px2, lx2) - fmaxf(px1, lx1), 0.f);
    const float ih = fmaxf(fminf(py2, ly2) - fmaxf(py1, ly1), 0.f);
    const float inter = iw * ih;
    const float uni = areap + areal - inter;
    const float iou = inter * frcp(uni);
    const float ew = fmaxf(fmaxf(px2, lx2) - fminf(px1, lx1), 0.f);
    const float eh = fmaxf(fmaxf(py2, ly2) - fminf(py1, ly1), 0.f);
    const float enc = ew * eh;
    const float giou = iou - (enc - uni) * frcp(enc);
    float g_sum = resp * (2.f - areal * (1.f / (608.f * 608.f))) * (1.f - giou);

    // ---- max IoU vs 150 GT boxes (b uniform per block -> scalar loads) ----
    const float* bb = bboxes + (size_t)b * (MAXGT * 4);
    float miou = 0.f;   // iou >= 0 always
    #pragma unroll 2
    for (int k = 0; k < MAXGT; ++k) {
        const float bx = bb[4 * k + 0], by = bb[4 * k + 1];
        const float bw = bb[4 * k + 2], bh = bb[4 * k + 3];
        const float bx1 = bx - bw * 0.5f, by1 = by - bh * 0.5f;
        const float bx2 = bx + bw * 0.5f, by2 = by + bh * 0.5f;
        const float kiw = fmaxf(fminf(px2, bx2) - fmaxf(px1, bx1), 0.f);
        const float kih = fmaxf(fminf(py2, by2) - fmaxf(py1, by1), 0.f);
        const float kint = kiw * kih;
        const float kuni = areap + bw * bh - kint;
        miou = fmaxf(miou, kint * frcp(kuni));
    }
    const float bgd = (1.f - resp) * ((miou < 0.5f) ? 1.f : 0.f);
    const float focal = (resp - pconf) * (resp - pconf);
    float c_sum = focal * (resp + bgd) * bcef(rc, resp);

    // ---- class prob BCE ----
    float ps = 0.f;
    #pragma unroll 4
    for (int c = 0; c < NCLS; ++c) {
        ps += bcef(cv[5 + c], lb[5 + c]);
    }
    float p_sum = resp * ps;

    if (!valid) { g_sum = 0.f; c_sum = 0.f; p_sum = 0.f; }

    // ---- block reduction ----
    for (int off = 32; off > 0; off >>= 1) {
        g_sum += __shfl_down(g_sum, off, 64);
        c_sum += __shfl_down(c_sum, off, 64);
        p_sum += __shfl_down(p_sum, off, 64);
    }
    __shared__ float sred[3][BLK / 64];
    const int lane = threadIdx.x & 63, wv = threadIdx.x >> 6;
    if (lane == 0) { sred[0][wv] = g_sum; sred[1][wv] = c_sum; sred[2][wv] = p_sum; }
    __syncthreads();
    if (threadIdx.x == 0) {
        float G = 0.f, C = 0.f, P = 0.f;
        #pragma unroll
        for (int w = 0; w < BLK / 64; ++w) { G += sred[0][w]; C += sred[1][w]; P += sred[2][w]; }
        const int bid = blockIdx.y * gridDim.x + blockIdx.x;
        part[bid * 3 + 0] = G;
        part[bid * 3 + 1] = C;
        part[bid * 3 + 2] = P;
    }
}

// Stage 2: deterministic tree reduction of per-block partials.
__global__ __launch_bounds__(64) void final_reduce(
    const float* __restrict__ part, float* __restrict__ out, int nblocks, float invB)
{
    const int lane = threadIdx.x;
    #pragma unroll
    for (int o = 0; o < 3; ++o) {
        float s = 0.f;
        for (int k = lane; k < nblocks; k += 64) s += part[(size_t)k * 3 + o];
        for (int off = 32; off > 0; off >>= 1) s += __shfl_down(s, off, 64);
        if (lane == 0) out[o] = s * invB;
    }
}

extern "C" void kernel_launch(void* const* d_in, const int* in_sizes, int n_in,
                              void* d_out, int out_size, void* d_ws, size_t ws_size,
                              hipStream_t stream) {
    const float* conv   = (const float*)d_in[0];
    const float* label  = (const float*)d_in[1];
    const float* bboxes = (const float*)d_in[2];
    float* out  = (float*)d_out;
    float* part = (float*)d_ws;

    const int B = in_sizes[2] / (MAXGT * 4);   // 16
    const int gx = (CELLS_PER_BATCH + BLK - 1) / BLK;   // 68
    dim3 grid(gx, B);
    yolo_loss_kernel<<<grid, BLK, 0, stream>>>(conv, label, bboxes, part);
    final_reduce<<<1, 64, 0, stream>>>(part, out, gx * B, 1.f / (float)B);
}

// Round 2
// 74.460 us; speedup vs baseline: 2.6720x; 2.6720x over previous
//
#include <hip/hip_runtime.h>
#include <math.h>

#define S 76
#define A 3
#define CH 85            // 5 + 80
#define NCLS 80
#define MAXGT 150
#define CPB (S * S * A)              // 17328 cells per batch
#define TILE 256                     // cells per block
#define BLK 256
#define F4_PER_TILE (TILE * CH / 4)  // 5440 float4 per full tile
#define FPB (CPB * CH)               // 1472880 floats per batch

__device__ __forceinline__ float frcp(float x) { return __builtin_amdgcn_rcpf(x); }
__device__ __forceinline__ float sigmoidf_(float x) { return frcp(1.f + __expf(-x)); }
// bce_with_logits(x, y) = max(x,0) - x*y + log1p(exp(-|x|))
__device__ __forceinline__ float bcef(float x, float y) {
    return fmaxf(x, 0.f) - x * y + __logf(1.f + __expf(-fabsf(x)));
}

__global__ __launch_bounds__(BLK) void yolo_loss_kernel(
    const float* __restrict__ conv, const float* __restrict__ label,
    const float* __restrict__ bboxes, float* __restrict__ part)
{
    __shared__ float4 s_box[MAXGT];   // x1,y1,x2,y2
    __shared__ float  s_ba[MAXGT];    // box area
    __shared__ float  s_resp[TILE];

    const int b    = blockIdx.y;
    const int tile = blockIdx.x;
    const int tid  = threadIdx.x;
    const int cell0 = tile * TILE;
    const int t = cell0 + tid;
    const bool valid = (t < CPB);
    const int tc = valid ? t : (CPB - 1);

    const size_t boff = (size_t)b * FPB;
    const float* cvb = conv  + boff;
    const float* lbb = label + boff;

    // ---- phase 0: GT boxes -> LDS; header loads (lines re-hit by phase 2 via L2) ----
    if (tid < MAXGT) {
        const float4 bx = *(const float4*)(bboxes + (size_t)b * (MAXGT * 4) + tid * 4);
        const float hw = bx.z * 0.5f, hh = bx.w * 0.5f;
        s_box[tid] = make_float4(bx.x - hw, bx.y - hh, bx.x + hw, bx.y + hh);
        s_ba[tid]  = bx.z * bx.w;
    }
    const float* cv = cvb + (size_t)tc * CH;
    const float* lb = lbb + (size_t)tc * CH;
    const float dx = cv[0], dy = cv[1], dw = cv[2], dh = cv[3], rc = cv[4];
    const float lx = lb[0], ly = lb[1], lw = lb[2], lh = lb[3], resp = lb[4];
    s_resp[tid] = valid ? resp : 0.f;
    __syncthreads();

    // ---- decode ----
    const int i   = tc / (S * A);
    const int rem = tc - i * (S * A);
    const int j   = rem / A;
    const int a   = rem - j * A;
    const float aw = (a == 0) ? 12.f : ((a == 1) ? 19.f : 40.f);
    const float ah = (a == 0) ? 16.f : ((a == 1) ? 36.f : 28.f);

    const float px = (sigmoidf_(dx) * 1.2f - 0.1f + (float)j) * 8.f;
    const float py = (sigmoidf_(dy) * 1.2f - 0.1f + (float)i) * 8.f;
    const float pw = __expf(dw) * aw;
    const float ph = __expf(dh) * ah;
    const float pconf = sigmoidf_(rc);

    // ---- GIoU(pred, label) ----
    const float px1 = px - pw * 0.5f, py1 = py - ph * 0.5f;
    const float px2 = px + pw * 0.5f, py2 = py + ph * 0.5f;
    const float lx1 = lx - lw * 0.5f, ly1 = ly - lh * 0.5f;
    const float lx2 = lx + lw * 0.5f, ly2 = ly + lh * 0.5f;
    const float areap = pw * ph, areal = lw * lh;
    const float iw = fmaxf(fminf(px2, lx2) - fmaxf(px1, lx1), 0.f);
    const float ih = fmaxf(fminf(py2, ly2) - fmaxf(py1, ly1), 0.f);
    const float inter = iw * ih;
    const float uni = areap + areal - inter;
    const float iou = inter * frcp(uni);
    const float ew = fmaxf(fmaxf(px2, lx2) - fminf(px1, lx1), 0.f);
    const float eh = fmaxf(fmaxf(py2, ly2) - fminf(py1, ly1), 0.f);
    const float enc = ew * eh;
    const float giou = iou - (enc - uni) * frcp(enc);
    float g_sum = resp * (2.f - areal * (1.f / (608.f * 608.f))) * (1.f - giou);

    // ---- bgd flag: max_iou<0.5  <=>  max_k(3*inter_k - area_k) < area_p  (division-free) ----
    float maxv = -1e30f;
    #pragma unroll 6
    for (int k = 0; k < MAXGT; ++k) {
        const float4 bx = s_box[k];      // broadcast LDS read
        const float ba  = s_ba[k];
        const float kiw = fmaxf(fminf(px2, bx.z) - fmaxf(px1, bx.x), 0.f);
        const float kih = fmaxf(fminf(py2, bx.w) - fmaxf(py1, bx.y), 0.f);
        maxv = fmaxf(maxv, __builtin_fmaf(3.f, kiw * kih, -ba));
    }
    const float bgd = (1.f - resp) * ((maxv < areap) ? 1.f : 0.f);
    const float focal = (resp - pconf) * (resp - pconf);
    float c_sum = focal * (resp + bgd) * bcef(rc, resp);

    if (!valid) { g_sum = 0.f; c_sum = 0.f; }

    // ---- phase 2: fully-coalesced float4 stream over tile's flat range ----
    const int n4 = min(F4_PER_TILE, (FPB - cell0 * CH) >> 2);
    const float4* cv4 = (const float4*)(cvb + (size_t)cell0 * CH);
    const float4* lb4 = (const float4*)(lbb + (size_t)cell0 * CH);
    float p_sum = 0.f;
    for (int u = tid; u < n4; u += BLK) {
        const float4 c4 = cv4[u];
        const float4 l4 = lb4[u];
        const int e0 = u << 2;
        const int c0 = e0 / CH;               // magic-mul division
        const int r0 = e0 - c0 * CH;
        const float ra = s_resp[c0];
        const float rb = s_resp[min(c0 + 1, TILE - 1)];
        const float cc[4] = {c4.x, c4.y, c4.z, c4.w};
        const float ll[4] = {l4.x, l4.y, l4.z, l4.w};
        #pragma unroll
        for (int k = 0; k < 4; ++k) {
            int r = r0 + k;
            float rsp = ra;
            if (r >= CH) { r -= CH; rsp = rb; }
            const float w = (r >= 5) ? rsp : 0.f;
            p_sum += w * bcef(cc[k], ll[k]);
        }
    }

    // ---- block reduction ----
    for (int off = 32; off > 0; off >>= 1) {
        g_sum += __shfl_down(g_sum, off, 64);
        c_sum += __shfl_down(c_sum, off, 64);
        p_sum += __shfl_down(p_sum, off, 64);
    }
    __shared__ float sred[3][BLK / 64];
    const int lane = threadIdx.x & 63, wv = threadIdx.x >> 6;
    if (lane == 0) { sred[0][wv] = g_sum; sred[1][wv] = c_sum; sred[2][wv] = p_sum; }
    __syncthreads();
    if (threadIdx.x == 0) {
        float G = 0.f, C = 0.f, P = 0.f;
        #pragma unroll
        for (int w = 0; w < BLK / 64; ++w) { G += sred[0][w]; C += sred[1][w]; P += sred[2][w]; }
        const int bid = blockIdx.y * gridDim.x + blockIdx.x;
        part[bid * 3 + 0] = G;
        part[bid * 3 + 1] = C;
        part[bid * 3 + 2] = P;
    }
}

__global__ __launch_bounds__(64) void final_reduce(
    const float* __restrict__ part, float* __restrict__ out, int nblocks, float invB)
{
    const int lane = threadIdx.x;
    #pragma unroll
    for (int o = 0; o < 3; ++o) {
        float s = 0.f;
        for (int k = lane; k < nblocks; k += 64) s += part[(size_t)k * 3 + o];
        for (int off = 32; off > 0; off >>= 1) s += __shfl_down(s, off, 64);
        if (lane == 0) out[o] = s * invB;
    }
}

extern "C" void kernel_launch(void* const* d_in, const int* in_sizes, int n_in,
                              void* d_out, int out_size, void* d_ws, size_t ws_size,
                              hipStream_t stream) {
    const float* conv   = (const float*)d_in[0];
    const float* label  = (const float*)d_in[1];
    const float* bboxes = (const float*)d_in[2];
    float* out  = (float*)d_out;
    float* part = (float*)d_ws;

    const int B = in_sizes[2] / (MAXGT * 4);          // 16
    const int gx = (CPB + TILE - 1) / TILE;           // 68
    dim3 grid(gx, B);
    yolo_loss_kernel<<<grid, BLK, 0, stream>>>(conv, label, bboxes, part);
    final_reduce<<<1, 64, 0, stream>>>(part, out, gx * B, 1.f / (float)B);
}

// Round 3
// 71.508 us; speedup vs baseline: 2.7824x; 1.0413x over previous
//
#include <hip/hip_runtime.h>
#include <math.h>

#define S 76
#define A 3
#define CH 85            // 5 + 80
#define NCLS 80
#define MAXGT 150
#define CPB (S * S * A)              // 17328 cells per batch
#define TILE 128                     // cells per block
#define BLK 256
#define F4_PER_TILE (TILE * CH / 4)  // 2720 float4 per full tile
#define FPB (CPB * CH)               // 1472880 floats per batch

__device__ __forceinline__ float frcp(float x) { return __builtin_amdgcn_rcpf(x); }
__device__ __forceinline__ float sigmoidf_(float x) { return frcp(1.f + __expf(-x)); }
// bce_with_logits(x, y) = max(x,0) - x*y + log1p(exp(-|x|))
__device__ __forceinline__ float bcef(float x, float y) {
    return fmaxf(x, 0.f) - x * y + __logf(1.f + __expf(-fabsf(x)));
}

__global__ __launch_bounds__(BLK) void yolo_loss_kernel(
    const float* __restrict__ conv, const float* __restrict__ label,
    const float* __restrict__ bboxes, float* __restrict__ part)
{
    __shared__ float4 s_box[MAXGT];   // 3*x1, y1, 3*x2, y2
    __shared__ float  s_ba[MAXGT];    // box area
    __shared__ float  s_resp[TILE];

    const int b    = blockIdx.y;
    const int tile = blockIdx.x;
    const int tid  = threadIdx.x;
    const int ci   = tid >> 1;          // cell within tile (pair-shared)
    const int pr   = tid & 1;           // parity: which half of the box list
    const int cell0 = tile * TILE;
    const int t = cell0 + ci;
    const bool valid = (t < CPB);
    const int tc = valid ? t : (CPB - 1);

    const size_t boff = (size_t)b * FPB;
    const float* cvb = conv  + boff;
    const float* lbb = label + boff;

    // ---- phase 0: GT boxes -> LDS (x-corners pre-scaled by 3) ----
    if (tid < MAXGT) {
        const float4 bx = *(const float4*)(bboxes + (size_t)b * (MAXGT * 4) + tid * 4);
        const float hw = bx.z * 0.5f, hh = bx.w * 0.5f;
        s_box[tid] = make_float4(3.f * (bx.x - hw), bx.y - hh, 3.f * (bx.x + hw), bx.y + hh);
        s_ba[tid]  = bx.z * bx.w;
    }
    const float* cv = cvb + (size_t)tc * CH;
    const float* lb = lbb + (size_t)tc * CH;
    const float dx = cv[0], dy = cv[1], dw = cv[2], dh = cv[3], rc = cv[4];
    const float lx = lb[0], ly = lb[1], lw = lb[2], lh = lb[3], resp = lb[4];
    if (pr == 0) s_resp[ci] = valid ? resp : 0.f;
    __syncthreads();

    // ---- decode (duplicated across the pair; cheap) ----
    const int i   = tc / (S * A);
    const int rem = tc - i * (S * A);
    const int j   = rem / A;
    const int a   = rem - j * A;
    const float aw = (a == 0) ? 12.f : ((a == 1) ? 19.f : 40.f);
    const float ah = (a == 0) ? 16.f : ((a == 1) ? 36.f : 28.f);

    const float px = (sigmoidf_(dx) * 1.2f - 0.1f + (float)j) * 8.f;
    const float py = (sigmoidf_(dy) * 1.2f - 0.1f + (float)i) * 8.f;
    const float pw = __expf(dw) * aw;
    const float ph = __expf(dh) * ah;
    const float pconf = sigmoidf_(rc);

    const float px1 = px - pw * 0.5f, py1 = py - ph * 0.5f;
    const float px2 = px + pw * 0.5f, py2 = py + ph * 0.5f;
    const float areap = pw * ph;

    // ---- bgd flag: max_iou<0.5  <=>  max_k(3*inter_k - area_k) < area_p ----
    // pair-split: parity lane scans boxes pr, pr+2, ..., combined via shfl_xor.
    const float px1_3 = 3.f * px1, px2_3 = 3.f * px2;
    float maxv = -1e30f;
    #pragma unroll 5
    for (int k = pr; k < MAXGT; k += 2) {
        const float4 bx = s_box[k];      // broadcast-pair LDS read
        const float ba  = s_ba[k];
        const float kiw3 = fmaxf(fminf(px2_3, bx.z) - fmaxf(px1_3, bx.x), 0.f);
        const float kih  = fmaxf(fminf(py2, bx.w) - fmaxf(py1, bx.y), 0.f);
        maxv = fmaxf(maxv, __builtin_fmaf(kiw3, kih, -ba));
    }
    maxv = fmaxf(maxv, __shfl_xor(maxv, 1, 64));

    float g_sum = 0.f, c_sum = 0.f;
    if (pr == 0 && valid) {
        // ---- GIoU(pred, label) ----
        const float lx1 = lx - lw * 0.5f, ly1 = ly - lh * 0.5f;
        const float lx2 = lx + lw * 0.5f, ly2 = ly + lh * 0.5f;
        const float areal = lw * lh;
        const float iw = fmaxf(fminf(px2, lx2) - fmaxf(px1, lx1), 0.f);
        const float ih = fmaxf(fminf(py2, ly2) - fmaxf(py1, ly1), 0.f);
        const float inter = iw * ih;
        const float uni = areap + areal - inter;
        const float iou = inter * frcp(uni);
        const float ew = fmaxf(fmaxf(px2, lx2) - fminf(px1, lx1), 0.f);
        const float eh = fmaxf(fmaxf(py2, ly2) - fminf(py1, ly1), 0.f);
        const float enc = ew * eh;
        const float giou = iou - (enc - uni) * frcp(enc);
        g_sum = resp * (2.f - areal * (1.f / (608.f * 608.f))) * (1.f - giou);

        const float bgd = (1.f - resp) * ((maxv < areap) ? 1.f : 0.f);
        const float focal = (resp - pconf) * (resp - pconf);
        c_sum = focal * (resp + bgd) * bcef(rc, resp);
    }

    // ---- phase 2: fully-coalesced float4 stream over tile's flat range ----
    const int n4 = min(F4_PER_TILE, (FPB - cell0 * CH) >> 2);
    const float4* cv4 = (const float4*)(cvb + (size_t)cell0 * CH);
    const float4* lb4 = (const float4*)(lbb + (size_t)cell0 * CH);
    float p_sum = 0.f;
    for (int u = tid; u < n4; u += BLK) {
        const float4 c4 = cv4[u];
        const float4 l4 = lb4[u];
        const int e0 = u << 2;
        const int c0 = e0 / CH;               // magic-mul division
        const int r0 = e0 - c0 * CH;
        const float ra = s_resp[c0];
        const float rb = s_resp[min(c0 + 1, TILE - 1)];
        const float cc[4] = {c4.x, c4.y, c4.z, c4.w};
        const float ll[4] = {l4.x, l4.y, l4.z, l4.w};
        #pragma unroll
        for (int k = 0; k < 4; ++k) {
            int r = r0 + k;
            float rsp = ra;
            if (r >= CH) { r -= CH; rsp = rb; }
            const float w = (r >= 5) ? rsp : 0.f;
            p_sum += w * bcef(cc[k], ll[k]);
        }
    }

    // ---- block reduction ----
    for (int off = 32; off > 0; off >>= 1) {
        g_sum += __shfl_down(g_sum, off, 64);
        c_sum += __shfl_down(c_sum, off, 64);
        p_sum += __shfl_down(p_sum, off, 64);
    }
    __shared__ float sred[3][BLK / 64];
    const int lane = threadIdx.x & 63, wv = threadIdx.x >> 6;
    if (lane == 0) { sred[0][wv] = g_sum; sred[1][wv] = c_sum; sred[2][wv] = p_sum; }
    __syncthreads();
    if (threadIdx.x == 0) {
        float G = 0.f, C = 0.f, P = 0.f;
        #pragma unroll
        for (int w = 0; w < BLK / 64; ++w) { G += sred[0][w]; C += sred[1][w]; P += sred[2][w]; }
        const int bid = blockIdx.y * gridDim.x + blockIdx.x;
        part[bid * 3 + 0] = G;
        part[bid * 3 + 1] = C;
        part[bid * 3 + 2] = P;
    }
}

__global__ __launch_bounds__(64) void final_reduce(
    const float* __restrict__ part, float* __restrict__ out, int nblocks, float invB)
{
    const int lane = threadIdx.x;
    #pragma unroll
    for (int o = 0; o < 3; ++o) {
        float s = 0.f;
        for (int k = lane; k < nblocks; k += 64) s += part[(size_t)k * 3 + o];
        for (int off = 32; off > 0; off >>= 1) s += __shfl_down(s, off, 64);
        if (lane == 0) out[o] = s * invB;
    }
}

extern "C" void kernel_launch(void* const* d_in, const int* in_sizes, int n_in,
                              void* d_out, int out_size, void* d_ws, size_t ws_size,
                              hipStream_t stream) {
    const float* conv   = (const float*)d_in[0];
    const float* label  = (const float*)d_in[1];
    const float* bboxes = (const float*)d_in[2];
    float* out  = (float*)d_out;
    float* part = (float*)d_ws;

    const int B = in_sizes[2] / (MAXGT * 4);          // 16
    const int gx = (CPB + TILE - 1) / TILE;           // 136
    dim3 grid(gx, B);
    yolo_loss_kernel<<<grid, BLK, 0, stream>>>(conv, label, bboxes, part);
    final_reduce<<<1, 64, 0, stream>>>(part, out, gx * B, 1.f / (float)B);
}